// Round 21
// baseline (103.547 us; speedup 1.0000x reference)
//
#include <hip/hip_runtime.h>
#include <hip/hip_bf16.h>

typedef __bf16 bf16x8 __attribute__((ext_vector_type(8)));
typedef float  f32x4  __attribute__((ext_vector_type(4)));
typedef float  f32x16 __attribute__((ext_vector_type(16)));

// async 16B global -> LDS (wave-uniform LDS base + lane*16)
__device__ __forceinline__ void gload_lds16(const void* g, void* l) {
  __builtin_amdgcn_global_load_lds(
      (const __attribute__((address_space(1))) unsigned int*)g,
      (__attribute__((address_space(3))) unsigned int*)l, 16, 0, 0);
}

// XCD-aware bijective remap for a (16, 32) grid: blocks sharing y land on ONE XCD.
__device__ __forceinline__ void xcd_remap(int& x, int& y) {
  const int lin = blockIdx.x + (blockIdx.y << 4);   // 0..511
  const int xcd = lin & 7, slot = lin >> 3;         // slot 0..63
  y = ((slot >> 4) << 3) + xcd;                     // 0..31
  x = slot & 15;                                    // 0..15
}

// ---------------- fused fp32 -> bf16 convert: x, Wq, Wo in one launch ----------------
__global__ void k_cvt3(const float* __restrict__ x, const float* __restrict__ wq,
                       const float* __restrict__ wo, __bf16* __restrict__ xb,
                       __bf16* __restrict__ wqb, __bf16* __restrict__ wob) {
  const int i = blockIdx.x * 256 + threadIdx.x;     // x 1M f4, wq 256K, wo 256K
  const float* s; __bf16* d; int j;
  if (i < 1048576)      { s = x;  d = xb;  j = i; }
  else if (i < 1310720) { s = wq; d = wqb; j = i - 1048576; }
  else                  { s = wo; d = wob; j = i - 1310720; }
  float4 v = ((const float4*)s)[j];
  union { __bf16 h[4]; uint2 u; } o;
  o.h[0] = (__bf16)v.x; o.h[1] = (__bf16)v.y;
  o.h[2] = (__bf16)v.z; o.h[3] = (__bf16)v.w;
  ((uint2*)d)[j] = o.u;
}

// ---------------- C[M,N] = A[M,K] @ B[N,K]^T + bias ---------------- (r20 proven, verbatim)
template<bool OUT_BF16>
__global__ __launch_bounds__(256, 2)
void k_gemm_bt(const __bf16* __restrict__ A, const __bf16* __restrict__ B,
               const float* __restrict__ bias, void* __restrict__ C,
               int M, int N, int K) {
  __shared__ __align__(16) __bf16 At[4][128 * 32];   // 32KB
  __shared__ __align__(16) __bf16 Bt[4][64 * 32];    // 16KB
  const int tid  = threadIdx.x;
  const int lane = tid & 63;
  const int w    = tid >> 6;
  const int wr   = w >> 1, wc = w & 1;
  int bx, by; xcd_remap(bx, by);
  const int bm = by * 128, bn = bx * 64;

  f32x4 acc[4][2] = {};

  const __bf16* ga = A + (size_t)(bm + (tid >> 2)) * K + (tid & 3) * 8;
  const __bf16* gb = B + (size_t)(bn + (tid >> 2)) * K + (tid & 3) * 8;

#pragma unroll
  for (int p = 0; p < 2; ++p) {
    gload_lds16(ga + p * 32,                  &At[p][(w * 16) * 32]);
    gload_lds16(ga + p * 32 + (size_t)64 * K, &At[p][(64 + w * 16) * 32]);
    gload_lds16(gb + p * 32,                  &Bt[p][(w * 16) * 32]);
  }

  const int NIT = K / 32;                      // 32
  for (int it = 0; it < NIT; ++it) {
    const int cur = it & 3;
    if (it + 2 < NIT) {
      const int nb = (it + 2) & 3;
      const int k2 = (it + 2) * 32;
      gload_lds16(ga + k2,                  &At[nb][(w * 16) * 32]);
      gload_lds16(ga + k2 + (size_t)64 * K, &At[nb][(64 + w * 16) * 32]);
      gload_lds16(gb + k2,                  &Bt[nb][(w * 16) * 32]);
      asm volatile("s_waitcnt vmcnt(6)" ::: "memory");
    } else if (it + 2 == NIT) {
      asm volatile("s_waitcnt vmcnt(3)" ::: "memory");
    } else {
      asm volatile("s_waitcnt vmcnt(0)" ::: "memory");
    }
    __builtin_amdgcn_s_barrier();
    __builtin_amdgcn_sched_barrier(0);

    bf16x8 a[4], b[2];
#pragma unroll
    for (int mt = 0; mt < 4; ++mt)
      a[mt] = *(const bf16x8*)&At[cur][(wr * 64 + mt * 16 + (lane & 15)) * 32 + (lane >> 4) * 8];
#pragma unroll
    for (int nt = 0; nt < 2; ++nt)
      b[nt] = *(const bf16x8*)&Bt[cur][(wc * 32 + nt * 16 + (lane & 15)) * 32 + (lane >> 4) * 8];
    __builtin_amdgcn_s_setprio(1);
#pragma unroll
    for (int mt = 0; mt < 4; ++mt)
#pragma unroll
      for (int nt = 0; nt < 2; ++nt)
        acc[mt][nt] = __builtin_amdgcn_mfma_f32_16x16x32_bf16(a[mt], b[nt], acc[mt][nt], 0, 0, 0);
    __builtin_amdgcn_s_setprio(0);
  }

#pragma unroll
  for (int nt = 0; nt < 2; ++nt) {
    const int col = bn + wc * 32 + nt * 16 + (lane & 15);
    const float bv = bias[col];
#pragma unroll
    for (int mt = 0; mt < 4; ++mt) {
#pragma unroll
      for (int r = 0; r < 4; ++r) {
        const int row = bm + wr * 64 + mt * 16 + (lane >> 4) * 4 + r;
        const float v = acc[mt][nt][r] + bv;
        if (OUT_BF16) ((__bf16*)C)[(size_t)row * N + col] = (__bf16)v;
        else          ((float*)C)[(size_t)row * N + col]  = v;
      }
    }
  }
}

// ---------------- flash attention (Q = K = V), 32x32x16, qf=2 (64 q/wave) ----------------
// r18-proven math per qf; K/V frags hoisted to registers and SHARED across both
// qf (halves LDS reads) and KV staged once per CU (grid (8,32) = 1 block/CU;
// halves LDS writes + global reads). Register peak ~236 unified < 512 cap at
// launch_bounds(256,1) -> no spill at 1 wave/SIMD.
#define SWZ2(row, col) ((row) * 64 + ((col) ^ (((((row) & 7) ^ ((row) >> 3)) & 7) << 3)))

#define ATTN_TILE(T, KB, VB)                                                  \
  {                                                                           \
    *(bf16x8*)&KB[SWZ2(2 * sm, c0)]     = v0;                                 \
    *(bf16x8*)&KB[SWZ2(2 * sm + 1, c0)] = v1;                                 \
    _Pragma("unroll")                                                         \
    for (int j = 0; j < 8; ++j) {                                             \
      union { __bf16 b[2]; unsigned u; } pk;                                  \
      pk.b[0] = v0[j]; pk.b[1] = v1[j];                                       \
      *(unsigned*)&VB[SWZ2(c0 + j, 2 * sm)] = pk.u;                           \
    }                                                                         \
    __syncthreads();                                                          \
    if ((T) < 31) {                                                           \
      v0 = *(const bf16x8*)&gsrc[(size_t)((T) + 1) * 64 * 1024];              \
      v1 = *(const bf16x8*)&gsrc[(size_t)((T) + 1) * 64 * 1024 + 1024];       \
    }                                                                         \
    bf16x8 ka[2][4];                                                          \
    _Pragma("unroll")                                                         \
    for (int kvf = 0; kvf < 2; ++kvf)                                         \
      _Pragma("unroll")                                                       \
      for (int ks = 0; ks < 4; ++ks)                                          \
        ka[kvf][ks] = *(const bf16x8*)&KB[SWZ2(kvf * 32 + l31, ks * 16 + h * 8)]; \
    unsigned P[2][2][4][2];                                                   \
    _Pragma("unroll")                                                         \
    for (int qf = 0; qf < 2; ++qf) {                                          \
      f32x16 s[2] = {};                                                       \
      __builtin_amdgcn_s_setprio(1);                                          \
      _Pragma("unroll")                                                       \
      for (int kvf = 0; kvf < 2; ++kvf)                                       \
        _Pragma("unroll")                                                     \
        for (int ks = 0; ks < 4; ++ks)                                        \
          s[kvf] = __builtin_amdgcn_mfma_f32_32x32x16_bf16(ka[kvf][ks], qb[qf][ks], s[kvf], 0, 0, 0); \
      __builtin_amdgcn_s_setprio(0);                                          \
      _Pragma("unroll")                                                       \
      for (int kvf = 0; kvf < 2; ++kvf) {                                     \
        _Pragma("unroll")                                                     \
        for (int rq = 0; rq < 4; ++rq) {                                      \
          _Pragma("unroll")                                                   \
          for (int tt = 0; tt < 2; ++tt) {                                    \
            const float p0 = __builtin_amdgcn_exp2f(s[kvf][rq * 4 + tt * 2]); \
            const float p1 = __builtin_amdgcn_exp2f(s[kvf][rq * 4 + tt * 2 + 1]); \
            union { __bf16 b[2]; unsigned u; } pk;                            \
            pk.b[0] = (__bf16)p0; pk.b[1] = (__bf16)p1;                       \
            P[qf][kvf][rq][tt] = pk.u;                                        \
          }                                                                   \
        }                                                                     \
      }                                                                       \
      _Pragma("unroll")                                                       \
      for (int ko = 0; ko < 4; ++ko) {                                        \
        const int kvf = ko >> 1, rqa = (ko & 1) * 2, rqb = rqa + 1;           \
        asm volatile("v_permlane32_swap_b32 %0, %1"                           \
                     : "+v"(P[qf][kvf][rqa][0]), "+v"(P[qf][kvf][rqb][0]));   \
        asm volatile("v_permlane32_swap_b32 %0, %1"                           \
                     : "+v"(P[qf][kvf][rqa][1]), "+v"(P[qf][kvf][rqb][1]));   \
      }                                                                       \
    }                                                                         \
    bf16x8 vb[2][4];                                                          \
    _Pragma("unroll")                                                         \
    for (int dh = 0; dh < 2; ++dh)                                            \
      _Pragma("unroll")                                                       \
      for (int ko = 0; ko < 4; ++ko)                                          \
        vb[dh][ko] = *(const bf16x8*)&VB[SWZ2(dh * 32 + l31, ko * 16 + h * 8)]; \
    __builtin_amdgcn_s_setprio(1);                                            \
    _Pragma("unroll")                                                         \
    for (int qf = 0; qf < 2; ++qf) {                                          \
      _Pragma("unroll")                                                       \
      for (int ko = 0; ko < 4; ++ko) {                                        \
        const int kvf = ko >> 1, rqa = (ko & 1) * 2, rqb = rqa + 1;           \
        union { unsigned u[4]; bf16x8 v; } pu;                                \
        pu.u[0] = P[qf][kvf][rqa][0]; pu.u[1] = P[qf][kvf][rqa][1];           \
        pu.u[2] = P[qf][kvf][rqb][0]; pu.u[3] = P[qf][kvf][rqb][1];           \
        Osum[qf] = __builtin_amdgcn_mfma_f32_32x32x16_bf16(pu.v, onesb, Osum[qf], 0, 0, 0); \
        O[qf][0] = __builtin_amdgcn_mfma_f32_32x32x16_bf16(pu.v, vb[0][ko], O[qf][0], 0, 0, 0); \
        O[qf][1] = __builtin_amdgcn_mfma_f32_32x32x16_bf16(pu.v, vb[1][ko], O[qf][1], 0, 0, 0); \
      }                                                                       \
    }                                                                         \
    __builtin_amdgcn_s_setprio(0);                                            \
  }

__global__ __launch_bounds__(256, 1)
void k_attn(const __bf16* __restrict__ q, __bf16* __restrict__ o) {
  __shared__ __align__(16) __bf16 Kt[2][64 * 64];
  __shared__ __align__(16) __bf16 Vt[2][64 * 64];
  const int tid = threadIdx.x, lane = tid & 63;
  const int w = tid >> 6;
  const int l31 = lane & 31, h = lane >> 5;
  // (8,32)-grid XCD remap: blocks sharing bh land on one XCD (4 heads/XCD)
  const int lin = blockIdx.x + (blockIdx.y << 3);   // 0..255
  const int xcd = lin & 7, slot = lin >> 3;         // 0..31
  const int bh = xcd + 8 * (slot >> 3);
  const int bqx = slot & 7;
  const size_t base = ((size_t)(bh >> 4) * 2048) * 1024 + (bh & 15) * 64;
  const int q0 = bqx * 256 + w * 64;
  const float c2 = 0.18033688f;     // 0.125 * log2(e)

  union { unsigned u[4]; bf16x8 v; } ones_u;
  ones_u.u[0] = 0x3F803F80u; ones_u.u[1] = 0x3F803F80u;
  ones_u.u[2] = 0x3F803F80u; ones_u.u[3] = 0x3F803F80u;
  const bf16x8 onesb = ones_u.v;

  // Q B-frags, PRE-SCALED by c2: qf selects q cols q0 + qf*32 + l31
  bf16x8 qb[2][4];
#pragma unroll
  for (int qf = 0; qf < 2; ++qf)
#pragma unroll
    for (int ks = 0; ks < 4; ++ks) {
      union { bf16x8 v; __bf16 b[8]; } u;
      u.v = *(const bf16x8*)&q[base + (size_t)(q0 + qf * 32 + l31) * 1024 + ks * 16 + h * 8];
#pragma unroll
      for (int j = 0; j < 8; ++j) u.b[j] = (__bf16)((float)u.b[j] * c2);
      qb[qf][ks] = u.v;
    }

  f32x16 O[2][2] = {};              // [qf][dh]; row q=(r&3)+8*(r>>2)+4h, col d=32dh+l31
  f32x16 Osum[2] = {};              // [qf]; row-sum of P, same row mapping

  // staging: thread covers kv rows 2sm, 2sm+1, cols c0..c0+7 (once per CU)
  const int sm = tid >> 3, c0 = (tid & 7) * 8;
  const __bf16* gsrc = q + base + (size_t)(2 * sm) * 1024 + c0;

  __bf16* const K0 = &Kt[0][0];  __bf16* const V0 = &Vt[0][0];
  __bf16* const K1 = &Kt[1][0];  __bf16* const V1 = &Vt[1][0];

  bf16x8 v0 = *(const bf16x8*)&gsrc[0];
  bf16x8 v1 = *(const bf16x8*)&gsrc[1024];

  for (int t2 = 0; t2 < 16; ++t2) {
    ATTN_TILE(2 * t2,     K0, V0)
    ATTN_TILE(2 * t2 + 1, K1, V1)
  }

  // ---- epilogue: O / Osum, store bf16
#pragma unroll
  for (int qf = 0; qf < 2; ++qf) {
#pragma unroll
    for (int r = 0; r < 16; ++r) {
      const int qrow = (r & 3) + 8 * (r >> 2) + 4 * h;
      const float rs = 1.0f / Osum[qf][r];
      o[base + (size_t)(q0 + qf * 32 + qrow) * 1024 + l31]      = (__bf16)(O[qf][0][r] * rs);
      o[base + (size_t)(q0 + qf * 32 + qrow) * 1024 + 32 + l31] = (__bf16)(O[qf][1][r] * rs);
    }
  }
}

// ---------------- launch ----------------
extern "C" void kernel_launch(void* const* d_in, const int* in_sizes, int n_in,
                              void* d_out, int out_size, void* d_ws, size_t ws_size,
                              hipStream_t stream) {
  const float* x  = (const float*)d_in[0];
  const float* Wq = (const float*)d_in[1];
  const float* bq = (const float*)d_in[2];
  const float* Wo = (const float*)d_in[3];
  const float* bo = (const float*)d_in[4];

  char* ws = (char*)d_ws;
  __bf16* xb  = (__bf16*)(ws);                          // [0,8)   x bf16
  __bf16* ab  = (__bf16*)(ws);                          // [0,8)   attn out (aliases xb; xb dead)
  __bf16* wqb = (__bf16*)(ws + ((size_t)8  << 20));     // [8,10)
  __bf16* wob = (__bf16*)(ws + ((size_t)10 << 20));     // [10,12)
  __bf16* qb  = (__bf16*)(ws + ((size_t)12 << 20));     // [12,20) q projection

  const int M = 4096, N = 1024, K = 1024;

  k_cvt3<<<6144, 256, 0, stream>>>(x, Wq, Wo, xb, wqb, wob);

  k_gemm_bt<true ><<<dim3(16, 32), 256, 0, stream>>>(xb, wqb, bq, qb, M, N, K);
  k_attn          <<<dim3(8, 32), 256, 0, stream>>>(qb, ab);
  k_gemm_bt<false><<<dim3(16, 32), 256, 0, stream>>>(ab, wob, bo, d_out, M, N, K);
}

// Round 22
// 94.333 us; speedup vs baseline: 1.0977x; 1.0977x over previous
//
#include <hip/hip_runtime.h>
#include <hip/hip_bf16.h>

typedef __bf16 bf16x8 __attribute__((ext_vector_type(8)));
typedef float  f32x4  __attribute__((ext_vector_type(4)));
typedef float  f32x16 __attribute__((ext_vector_type(16)));

// async 16B global -> LDS (wave-uniform LDS base + lane*16)
__device__ __forceinline__ void gload_lds16(const void* g, void* l) {
  __builtin_amdgcn_global_load_lds(
      (const __attribute__((address_space(1))) unsigned int*)g,
      (__attribute__((address_space(3))) unsigned int*)l, 16, 0, 0);
}

// XCD-aware bijective remap for a (16, 32) grid: blocks sharing y land on ONE XCD.
__device__ __forceinline__ void xcd_remap(int& x, int& y) {
  const int lin = blockIdx.x + (blockIdx.y << 4);   // 0..511
  const int xcd = lin & 7, slot = lin >> 3;         // slot 0..63
  y = ((slot >> 4) << 3) + xcd;                     // 0..31
  x = slot & 15;                                    // 0..15
}

// ---------------- fused fp32 -> bf16 convert: x, Wq, Wo in one launch ----------------
__global__ void k_cvt3(const float* __restrict__ x, const float* __restrict__ wq,
                       const float* __restrict__ wo, __bf16* __restrict__ xb,
                       __bf16* __restrict__ wqb, __bf16* __restrict__ wob) {
  const int i = blockIdx.x * 256 + threadIdx.x;     // x 1M f4, wq 256K, wo 256K
  const float* s; __bf16* d; int j;
  if (i < 1048576)      { s = x;  d = xb;  j = i; }
  else if (i < 1310720) { s = wq; d = wqb; j = i - 1048576; }
  else                  { s = wo; d = wob; j = i - 1310720; }
  float4 v = ((const float4*)s)[j];
  union { __bf16 h[4]; uint2 u; } o;
  o.h[0] = (__bf16)v.x; o.h[1] = (__bf16)v.y;
  o.h[2] = (__bf16)v.z; o.h[3] = (__bf16)v.w;
  ((uint2*)d)[j] = o.u;
}

// ---------------- C[M,N] = A[M,K] @ B[N,K]^T + bias ----------------
// r16/r20-proven: 128x64 tile, BK=32, 4 buffers, depth-2 prefetch, counted
// vmcnt(6), one raw barrier/iter, XCD remap. 512 blocks = 2 blk/CU (8 waves/CU).
template<bool OUT_BF16>
__global__ __launch_bounds__(256, 2)
void k_gemm_bt(const __bf16* __restrict__ A, const __bf16* __restrict__ B,
               const float* __restrict__ bias, void* __restrict__ C,
               int M, int N, int K) {
  __shared__ __align__(16) __bf16 At[4][128 * 32];   // 32KB
  __shared__ __align__(16) __bf16 Bt[4][64 * 32];    // 16KB
  const int tid  = threadIdx.x;
  const int lane = tid & 63;
  const int w    = tid >> 6;
  const int wr   = w >> 1, wc = w & 1;
  int bx, by; xcd_remap(bx, by);
  const int bm = by * 128, bn = bx * 64;

  f32x4 acc[4][2] = {};

  const __bf16* ga = A + (size_t)(bm + (tid >> 2)) * K + (tid & 3) * 8;
  const __bf16* gb = B + (size_t)(bn + (tid >> 2)) * K + (tid & 3) * 8;

#pragma unroll
  for (int p = 0; p < 2; ++p) {
    gload_lds16(ga + p * 32,                  &At[p][(w * 16) * 32]);
    gload_lds16(ga + p * 32 + (size_t)64 * K, &At[p][(64 + w * 16) * 32]);
    gload_lds16(gb + p * 32,                  &Bt[p][(w * 16) * 32]);
  }

  const int NIT = K / 32;                      // 32
  for (int it = 0; it < NIT; ++it) {
    const int cur = it & 3;
    if (it + 2 < NIT) {
      const int nb = (it + 2) & 3;
      const int k2 = (it + 2) * 32;
      gload_lds16(ga + k2,                  &At[nb][(w * 16) * 32]);
      gload_lds16(ga + k2 + (size_t)64 * K, &At[nb][(64 + w * 16) * 32]);
      gload_lds16(gb + k2,                  &Bt[nb][(w * 16) * 32]);
      asm volatile("s_waitcnt vmcnt(6)" ::: "memory");
    } else if (it + 2 == NIT) {
      asm volatile("s_waitcnt vmcnt(3)" ::: "memory");
    } else {
      asm volatile("s_waitcnt vmcnt(0)" ::: "memory");
    }
    __builtin_amdgcn_s_barrier();
    __builtin_amdgcn_sched_barrier(0);

    bf16x8 a[4], b[2];
#pragma unroll
    for (int mt = 0; mt < 4; ++mt)
      a[mt] = *(const bf16x8*)&At[cur][(wr * 64 + mt * 16 + (lane & 15)) * 32 + (lane >> 4) * 8];
#pragma unroll
    for (int nt = 0; nt < 2; ++nt)
      b[nt] = *(const bf16x8*)&Bt[cur][(wc * 32 + nt * 16 + (lane & 15)) * 32 + (lane >> 4) * 8];
    __builtin_amdgcn_s_setprio(1);
#pragma unroll
    for (int mt = 0; mt < 4; ++mt)
#pragma unroll
      for (int nt = 0; nt < 2; ++nt)
        acc[mt][nt] = __builtin_amdgcn_mfma_f32_16x16x32_bf16(a[mt], b[nt], acc[mt][nt], 0, 0, 0);
    __builtin_amdgcn_s_setprio(0);
  }

#pragma unroll
  for (int nt = 0; nt < 2; ++nt) {
    const int col = bn + wc * 32 + nt * 16 + (lane & 15);
    const float bv = bias[col];
#pragma unroll
    for (int mt = 0; mt < 4; ++mt) {
#pragma unroll
      for (int r = 0; r < 4; ++r) {
        const int row = bm + wr * 64 + mt * 16 + (lane >> 4) * 4 + r;
        const float v = acc[mt][nt][r] + bv;
        if (OUT_BF16) ((__bf16*)C)[(size_t)row * N + col] = (__bf16)v;
        else          ((float*)C)[(size_t)row * N + col]  = v;
      }
    }
  }
}

// ---------------- flash attention (Q = K = V), 32x32x16 MFMA ---------------- (r18/r20 proven, verbatim)
#define SWZ2(row, col) ((row) * 64 + ((col) ^ (((((row) & 7) ^ ((row) >> 3)) & 7) << 3)))

#define ATTN_TILE(T, KB, VB)                                                  \
  {                                                                           \
    *(bf16x8*)&KB[SWZ2(2 * sm, c0)]     = v0;                                 \
    *(bf16x8*)&KB[SWZ2(2 * sm + 1, c0)] = v1;                                 \
    _Pragma("unroll")                                                         \
    for (int j = 0; j < 8; ++j) {                                             \
      union { __bf16 b[2]; unsigned u; } pk;                                  \
      pk.b[0] = v0[j]; pk.b[1] = v1[j];                                       \
      *(unsigned*)&VB[SWZ2(c0 + j, 2 * sm)] = pk.u;                           \
    }                                                                         \
    __syncthreads();                                                          \
    if ((T) < 31) {                                                           \
      v0 = *(const bf16x8*)&gsrc[(size_t)((T) + 1) * 64 * 1024];              \
      v1 = *(const bf16x8*)&gsrc[(size_t)((T) + 1) * 64 * 1024 + 1024];       \
    }                                                                         \
    f32x16 s[2] = {};                                                         \
    _Pragma("unroll")                                                         \
    for (int kvf = 0; kvf < 2; ++kvf) {                                       \
      __builtin_amdgcn_s_setprio(1);                                          \
      _Pragma("unroll")                                                       \
      for (int ks = 0; ks < 4; ++ks) {                                        \
        bf16x8 ka = *(const bf16x8*)&KB[SWZ2(kvf * 32 + l31, ks * 16 + h * 8)]; \
        s[kvf] = __builtin_amdgcn_mfma_f32_32x32x16_bf16(ka, qb[ks], s[kvf], 0, 0, 0); \
      }                                                                       \
      __builtin_amdgcn_s_setprio(0);                                          \
    }                                                                         \
    unsigned P[2][4][2];                                                      \
    _Pragma("unroll")                                                         \
    for (int kvf = 0; kvf < 2; ++kvf) {                                       \
      _Pragma("unroll")                                                       \
      for (int rq = 0; rq < 4; ++rq) {                                        \
        _Pragma("unroll")                                                     \
        for (int tt = 0; tt < 2; ++tt) {                                      \
          const float p0 = __builtin_amdgcn_exp2f(s[kvf][rq * 4 + tt * 2]);   \
          const float p1 = __builtin_amdgcn_exp2f(s[kvf][rq * 4 + tt * 2 + 1]); \
          union { __bf16 b[2]; unsigned u; } pk;                              \
          pk.b[0] = (__bf16)p0; pk.b[1] = (__bf16)p1;                         \
          P[kvf][rq][tt] = pk.u;                                              \
        }                                                                     \
      }                                                                       \
    }                                                                         \
    _Pragma("unroll")                                                         \
    for (int ko = 0; ko < 4; ++ko) {                                          \
      const int kvf = ko >> 1, rqa = (ko & 1) * 2, rqb = rqa + 1;             \
      asm volatile("v_permlane32_swap_b32 %0, %1"                             \
                   : "+v"(P[kvf][rqa][0]), "+v"(P[kvf][rqb][0]));             \
      asm volatile("v_permlane32_swap_b32 %0, %1"                             \
                   : "+v"(P[kvf][rqa][1]), "+v"(P[kvf][rqb][1]));             \
    }                                                                         \
    __builtin_amdgcn_s_setprio(1);                                            \
    _Pragma("unroll")                                                         \
    for (int ko = 0; ko < 4; ++ko) {                                          \
      const int kvf = ko >> 1, rqa = (ko & 1) * 2, rqb = rqa + 1;             \
      union { unsigned u[4]; bf16x8 v; } pu;                                  \
      pu.u[0] = P[kvf][rqa][0]; pu.u[1] = P[kvf][rqa][1];                     \
      pu.u[2] = P[kvf][rqb][0]; pu.u[3] = P[kvf][rqb][1];                     \
      Osum = __builtin_amdgcn_mfma_f32_32x32x16_bf16(pu.v, onesb, Osum, 0, 0, 0); \
      bf16x8 vb0 = *(const bf16x8*)&VB[SWZ2(l31,      ko * 16 + h * 8)];      \
      bf16x8 vb1 = *(const bf16x8*)&VB[SWZ2(32 + l31, ko * 16 + h * 8)];      \
      O[0] = __builtin_amdgcn_mfma_f32_32x32x16_bf16(pu.v, vb0, O[0], 0, 0, 0); \
      O[1] = __builtin_amdgcn_mfma_f32_32x32x16_bf16(pu.v, vb1, O[1], 0, 0, 0); \
    }                                                                         \
    __builtin_amdgcn_s_setprio(0);                                            \
  }

__global__ __launch_bounds__(256, 2)
void k_attn(const __bf16* __restrict__ q, __bf16* __restrict__ o) {
  __shared__ __align__(16) __bf16 Kt[2][64 * 64];
  __shared__ __align__(16) __bf16 Vt[2][64 * 64];
  const int tid = threadIdx.x, lane = tid & 63;
  const int w = tid >> 6;
  const int l31 = lane & 31, h = lane >> 5;
  int bqx, bh; xcd_remap(bqx, bh);
  const size_t base = ((size_t)(bh >> 4) * 2048) * 1024 + (bh & 15) * 64;
  const int q0 = bqx * 128 + w * 32;
  const float c2 = 0.18033688f;     // 0.125 * log2(e)

  union { unsigned u[4]; bf16x8 v; } ones_u;
  ones_u.u[0] = 0x3F803F80u; ones_u.u[1] = 0x3F803F80u;
  ones_u.u[2] = 0x3F803F80u; ones_u.u[3] = 0x3F803F80u;
  const bf16x8 onesb = ones_u.v;

  bf16x8 qb[4];
#pragma unroll
  for (int ks = 0; ks < 4; ++ks) {
    union { bf16x8 v; __bf16 b[8]; } u;
    u.v = *(const bf16x8*)&q[base + (size_t)(q0 + l31) * 1024 + ks * 16 + h * 8];
#pragma unroll
    for (int j = 0; j < 8; ++j) u.b[j] = (__bf16)((float)u.b[j] * c2);
    qb[ks] = u.v;
  }

  f32x16 O[2] = {};
  f32x16 Osum = {};

  const int sm = tid >> 3, c0 = (tid & 7) * 8;
  const __bf16* gsrc = q + base + (size_t)(2 * sm) * 1024 + c0;

  __bf16* const K0 = &Kt[0][0];  __bf16* const V0 = &Vt[0][0];
  __bf16* const K1 = &Kt[1][0];  __bf16* const V1 = &Vt[1][0];

  bf16x8 v0 = *(const bf16x8*)&gsrc[0];
  bf16x8 v1 = *(const bf16x8*)&gsrc[1024];

  for (int t2 = 0; t2 < 16; ++t2) {
    ATTN_TILE(2 * t2,     K0, V0)
    ATTN_TILE(2 * t2 + 1, K1, V1)
  }

#pragma unroll
  for (int r = 0; r < 16; ++r) {
    const int qrow = (r & 3) + 8 * (r >> 2) + 4 * h;
    const float rs = 1.0f / Osum[r];
    o[base + (size_t)(q0 + qrow) * 1024 + l31]      = (__bf16)(O[0][r] * rs);
    o[base + (size_t)(q0 + qrow) * 1024 + 32 + l31] = (__bf16)(O[1][r] * rs);
  }
}

// ---------------- launch ----------------
extern "C" void kernel_launch(void* const* d_in, const int* in_sizes, int n_in,
                              void* d_out, int out_size, void* d_ws, size_t ws_size,
                              hipStream_t stream) {
  const float* x  = (const float*)d_in[0];
  const float* Wq = (const float*)d_in[1];
  const float* bq = (const float*)d_in[2];
  const float* Wo = (const float*)d_in[3];
  const float* bo = (const float*)d_in[4];

  char* ws = (char*)d_ws;
  __bf16* xb  = (__bf16*)(ws);                          // [0,8)   x bf16
  __bf16* ab  = (__bf16*)(ws);                          // [0,8)   attn out (aliases xb; xb dead)
  __bf16* wqb = (__bf16*)(ws + ((size_t)8  << 20));     // [8,10)
  __bf16* wob = (__bf16*)(ws + ((size_t)10 << 20));     // [10,12)
  __bf16* qb  = (__bf16*)(ws + ((size_t)12 << 20));     // [12,20) q projection

  const int M = 4096, N = 1024, K = 1024;

  k_cvt3<<<6144, 256, 0, stream>>>(x, Wq, Wo, xb, wqb, wob);

  k_gemm_bt<true ><<<dim3(16, 32), 256, 0, stream>>>(xb, wqb, bq, qb, M, N, K);
  k_attn          <<<dim3(16, 32), 256, 0, stream>>>(qb, ab);
  k_gemm_bt<false><<<dim3(16, 32), 256, 0, stream>>>(ab, wob, bo, d_out, M, N, K);
}

// Round 23
// 94.128 us; speedup vs baseline: 1.1001x; 1.0022x over previous
//
#include <hip/hip_runtime.h>
#include <hip/hip_bf16.h>

typedef __bf16 bf16x8 __attribute__((ext_vector_type(8)));
typedef float  f32x4  __attribute__((ext_vector_type(4)));
typedef float  f32x16 __attribute__((ext_vector_type(16)));

// async 16B global -> LDS (wave-uniform LDS base + lane*16)
__device__ __forceinline__ void gload_lds16(const void* g, void* l) {
  __builtin_amdgcn_global_load_lds(
      (const __attribute__((address_space(1))) unsigned int*)g,
      (__attribute__((address_space(3))) unsigned int*)l, 16, 0, 0);
}

// XCD-aware bijective remap for a (16, 32) grid: blocks sharing y land on ONE XCD.
__device__ __forceinline__ void xcd_remap(int& x, int& y) {
  const int lin = blockIdx.x + (blockIdx.y << 4);   // 0..511
  const int xcd = lin & 7, slot = lin >> 3;         // slot 0..63
  y = ((slot >> 4) << 3) + xcd;                     // 0..31
  x = slot & 15;                                    // 0..15
}

// ---------------- fused fp32 -> bf16 convert: x, Wq, Wo in one launch ----------------
__global__ void k_cvt3(const float* __restrict__ x, const float* __restrict__ wq,
                       const float* __restrict__ wo, __bf16* __restrict__ xb,
                       __bf16* __restrict__ wqb, __bf16* __restrict__ wob) {
  const int i = blockIdx.x * 256 + threadIdx.x;     // x 1M f4, wq 256K, wo 256K
  const float* s; __bf16* d; int j;
  if (i < 1048576)      { s = x;  d = xb;  j = i; }
  else if (i < 1310720) { s = wq; d = wqb; j = i - 1048576; }
  else                  { s = wo; d = wob; j = i - 1310720; }
  float4 v = ((const float4*)s)[j];
  union { __bf16 h[4]; uint2 u; } o;
  o.h[0] = (__bf16)v.x; o.h[1] = (__bf16)v.y;
  o.h[2] = (__bf16)v.z; o.h[3] = (__bf16)v.w;
  ((uint2*)d)[j] = o.u;
}

// ---------------- C[M,N] = A[M,K] @ B[N,K]^T + bias ---------------- (r22 proven, verbatim)
template<bool OUT_BF16>
__global__ __launch_bounds__(256, 2)
void k_gemm_bt(const __bf16* __restrict__ A, const __bf16* __restrict__ B,
               const float* __restrict__ bias, void* __restrict__ C,
               int M, int N, int K) {
  __shared__ __align__(16) __bf16 At[4][128 * 32];   // 32KB
  __shared__ __align__(16) __bf16 Bt[4][64 * 32];    // 16KB
  const int tid  = threadIdx.x;
  const int lane = tid & 63;
  const int w    = tid >> 6;
  const int wr   = w >> 1, wc = w & 1;
  int bx, by; xcd_remap(bx, by);
  const int bm = by * 128, bn = bx * 64;

  f32x4 acc[4][2] = {};

  const __bf16* ga = A + (size_t)(bm + (tid >> 2)) * K + (tid & 3) * 8;
  const __bf16* gb = B + (size_t)(bn + (tid >> 2)) * K + (tid & 3) * 8;

#pragma unroll
  for (int p = 0; p < 2; ++p) {
    gload_lds16(ga + p * 32,                  &At[p][(w * 16) * 32]);
    gload_lds16(ga + p * 32 + (size_t)64 * K, &At[p][(64 + w * 16) * 32]);
    gload_lds16(gb + p * 32,                  &Bt[p][(w * 16) * 32]);
  }

  const int NIT = K / 32;                      // 32
  for (int it = 0; it < NIT; ++it) {
    const int cur = it & 3;
    if (it + 2 < NIT) {
      const int nb = (it + 2) & 3;
      const int k2 = (it + 2) * 32;
      gload_lds16(ga + k2,                  &At[nb][(w * 16) * 32]);
      gload_lds16(ga + k2 + (size_t)64 * K, &At[nb][(64 + w * 16) * 32]);
      gload_lds16(gb + k2,                  &Bt[nb][(w * 16) * 32]);
      asm volatile("s_waitcnt vmcnt(6)" ::: "memory");
    } else if (it + 2 == NIT) {
      asm volatile("s_waitcnt vmcnt(3)" ::: "memory");
    } else {
      asm volatile("s_waitcnt vmcnt(0)" ::: "memory");
    }
    __builtin_amdgcn_s_barrier();
    __builtin_amdgcn_sched_barrier(0);

    bf16x8 a[4], b[2];
#pragma unroll
    for (int mt = 0; mt < 4; ++mt)
      a[mt] = *(const bf16x8*)&At[cur][(wr * 64 + mt * 16 + (lane & 15)) * 32 + (lane >> 4) * 8];
#pragma unroll
    for (int nt = 0; nt < 2; ++nt)
      b[nt] = *(const bf16x8*)&Bt[cur][(wc * 32 + nt * 16 + (lane & 15)) * 32 + (lane >> 4) * 8];
    __builtin_amdgcn_s_setprio(1);
#pragma unroll
    for (int mt = 0; mt < 4; ++mt)
#pragma unroll
      for (int nt = 0; nt < 2; ++nt)
        acc[mt][nt] = __builtin_amdgcn_mfma_f32_16x16x32_bf16(a[mt], b[nt], acc[mt][nt], 0, 0, 0);
    __builtin_amdgcn_s_setprio(0);
  }

#pragma unroll
  for (int nt = 0; nt < 2; ++nt) {
    const int col = bn + wc * 32 + nt * 16 + (lane & 15);
    const float bv = bias[col];
#pragma unroll
    for (int mt = 0; mt < 4; ++mt) {
#pragma unroll
      for (int r = 0; r < 4; ++r) {
        const int row = bm + wr * 64 + mt * 16 + (lane >> 4) * 4 + r;
        const float v = acc[mt][nt][r] + bv;
        if (OUT_BF16) ((__bf16*)C)[(size_t)row * N + col] = (__bf16)v;
        else          ((float*)C)[(size_t)row * N + col]  = v;
      }
    }
  }
}

// ---------------- flash attention (Q = K = V), 32x32x16, PAIR-PHASE ----------------
// r18/r22-proven per-tile math, restructured: TWO 64-kv tiles staged per barrier
// into 4 single-tile buffers (same SWZ2 layout), both computed back-to-back.
// Halves barrier count (32->16) and exposes cross-tile ILP (tile B's MFMA hides
// tile A's exp2 chain). Race: phase p writes pair p&1; previous phase read the
// OTHER pair; this pair's reads finished 2 phases ago (before previous barrier).
#define SWZ2(row, col) ((row) * 64 + ((col) ^ (((((row) & 7) ^ ((row) >> 3)) & 7) << 3)))

#define WRITE_TILE(KB, VB, va, vb2)                                           \
    *(bf16x8*)&KB[SWZ2(2 * sm, c0)]     = va;                                 \
    *(bf16x8*)&KB[SWZ2(2 * sm + 1, c0)] = vb2;                                \
    _Pragma("unroll")                                                         \
    for (int j = 0; j < 8; ++j) {                                             \
      union { __bf16 b[2]; unsigned u; } pk;                                  \
      pk.b[0] = va[j]; pk.b[1] = vb2[j];                                      \
      *(unsigned*)&VB[SWZ2(c0 + j, 2 * sm)] = pk.u;                           \
    }

#define COMPUTE_TILE(KB, VB)                                                  \
  {                                                                           \
    f32x16 s[2] = {};                                                         \
    _Pragma("unroll")                                                         \
    for (int kvf = 0; kvf < 2; ++kvf) {                                       \
      __builtin_amdgcn_s_setprio(1);                                          \
      _Pragma("unroll")                                                       \
      for (int ks = 0; ks < 4; ++ks) {                                        \
        bf16x8 ka = *(const bf16x8*)&KB[SWZ2(kvf * 32 + l31, ks * 16 + h * 8)]; \
        s[kvf] = __builtin_amdgcn_mfma_f32_32x32x16_bf16(ka, qb[ks], s[kvf], 0, 0, 0); \
      }                                                                       \
      __builtin_amdgcn_s_setprio(0);                                          \
    }                                                                         \
    unsigned P[2][4][2];                                                      \
    _Pragma("unroll")                                                         \
    for (int kvf = 0; kvf < 2; ++kvf) {                                       \
      _Pragma("unroll")                                                       \
      for (int rq = 0; rq < 4; ++rq) {                                        \
        _Pragma("unroll")                                                     \
        for (int tt = 0; tt < 2; ++tt) {                                      \
          const float p0 = __builtin_amdgcn_exp2f(s[kvf][rq * 4 + tt * 2]);   \
          const float p1 = __builtin_amdgcn_exp2f(s[kvf][rq * 4 + tt * 2 + 1]); \
          union { __bf16 b[2]; unsigned u; } pk;                              \
          pk.b[0] = (__bf16)p0; pk.b[1] = (__bf16)p1;                         \
          P[kvf][rq][tt] = pk.u;                                              \
        }                                                                     \
      }                                                                       \
    }                                                                         \
    _Pragma("unroll")                                                         \
    for (int ko = 0; ko < 4; ++ko) {                                          \
      const int kvf = ko >> 1, rqa = (ko & 1) * 2, rqb = rqa + 1;             \
      asm volatile("v_permlane32_swap_b32 %0, %1"                             \
                   : "+v"(P[kvf][rqa][0]), "+v"(P[kvf][rqb][0]));             \
      asm volatile("v_permlane32_swap_b32 %0, %1"                             \
                   : "+v"(P[kvf][rqa][1]), "+v"(P[kvf][rqb][1]));             \
    }                                                                         \
    __builtin_amdgcn_s_setprio(1);                                            \
    _Pragma("unroll")                                                         \
    for (int ko = 0; ko < 4; ++ko) {                                          \
      const int kvf = ko >> 1, rqa = (ko & 1) * 2, rqb = rqa + 1;             \
      union { unsigned u[4]; bf16x8 v; } pu;                                  \
      pu.u[0] = P[kvf][rqa][0]; pu.u[1] = P[kvf][rqa][1];                     \
      pu.u[2] = P[kvf][rqb][0]; pu.u[3] = P[kvf][rqb][1];                     \
      Osum = __builtin_amdgcn_mfma_f32_32x32x16_bf16(pu.v, onesb, Osum, 0, 0, 0); \
      bf16x8 vb0 = *(const bf16x8*)&VB[SWZ2(l31,      ko * 16 + h * 8)];      \
      bf16x8 vb1 = *(const bf16x8*)&VB[SWZ2(32 + l31, ko * 16 + h * 8)];      \
      O[0] = __builtin_amdgcn_mfma_f32_32x32x16_bf16(pu.v, vb0, O[0], 0, 0, 0); \
      O[1] = __builtin_amdgcn_mfma_f32_32x32x16_bf16(pu.v, vb1, O[1], 0, 0, 0); \
    }                                                                         \
    __builtin_amdgcn_s_setprio(0);                                            \
  }

#define PHASE(T, KA, VA, KB, VB)                                              \
  {                                                                           \
    WRITE_TILE(KA, VA, v0, v1)                                                \
    WRITE_TILE(KB, VB, v2, v3)                                                \
    __syncthreads();                                                          \
    if ((T) < 30) {                                                           \
      v0 = *(const bf16x8*)&gsrc[(size_t)((T) + 2) * 64 * 1024];              \
      v1 = *(const bf16x8*)&gsrc[(size_t)((T) + 2) * 64 * 1024 + 1024];       \
      v2 = *(const bf16x8*)&gsrc[(size_t)((T) + 3) * 64 * 1024];              \
      v3 = *(const bf16x8*)&gsrc[(size_t)((T) + 3) * 64 * 1024 + 1024];       \
    }                                                                         \
    COMPUTE_TILE(KA, VA)                                                      \
    COMPUTE_TILE(KB, VB)                                                      \
  }

__global__ __launch_bounds__(256, 2)
void k_attn(const __bf16* __restrict__ q, __bf16* __restrict__ o) {
  __shared__ __align__(16) __bf16 Kt[4][64 * 64];   // 32KB
  __shared__ __align__(16) __bf16 Vt[4][64 * 64];   // 32KB
  const int tid = threadIdx.x, lane = tid & 63;
  const int w = tid >> 6;
  const int l31 = lane & 31, h = lane >> 5;
  int bqx, bh; xcd_remap(bqx, bh);
  const size_t base = ((size_t)(bh >> 4) * 2048) * 1024 + (bh & 15) * 64;
  const int q0 = bqx * 128 + w * 32;
  const float c2 = 0.18033688f;     // 0.125 * log2(e)

  union { unsigned u[4]; bf16x8 v; } ones_u;
  ones_u.u[0] = 0x3F803F80u; ones_u.u[1] = 0x3F803F80u;
  ones_u.u[2] = 0x3F803F80u; ones_u.u[3] = 0x3F803F80u;
  const bf16x8 onesb = ones_u.v;

  // Q B-frags, PRE-SCALED by c2: col q = q0+l31, k(d) = 16ks + 8h + 0..7
  bf16x8 qb[4];
#pragma unroll
  for (int ks = 0; ks < 4; ++ks) {
    union { bf16x8 v; __bf16 b[8]; } u;
    u.v = *(const bf16x8*)&q[base + (size_t)(q0 + l31) * 1024 + ks * 16 + h * 8];
#pragma unroll
    for (int j = 0; j < 8; ++j) u.b[j] = (__bf16)((float)u.b[j] * c2);
    qb[ks] = u.v;
  }

  f32x16 O[2] = {};                 // row q=(r&3)+8*(r>>2)+4h, col d=32dh+l31
  f32x16 Osum = {};                 // row-sum of P, same row mapping

  // staging: thread covers kv rows 2sm, 2sm+1, cols c0..c0+7
  const int sm = tid >> 3, c0 = (tid & 7) * 8;
  const __bf16* gsrc = q + base + (size_t)(2 * sm) * 1024 + c0;

  __bf16* const K0 = &Kt[0][0];  __bf16* const V0 = &Vt[0][0];
  __bf16* const K1 = &Kt[1][0];  __bf16* const V1 = &Vt[1][0];
  __bf16* const K2 = &Kt[2][0];  __bf16* const V2 = &Vt[2][0];
  __bf16* const K3 = &Kt[3][0];  __bf16* const V3 = &Vt[3][0];

  // prologue: tiles 0,1 into registers
  bf16x8 v0 = *(const bf16x8*)&gsrc[0];
  bf16x8 v1 = *(const bf16x8*)&gsrc[1024];
  bf16x8 v2 = *(const bf16x8*)&gsrc[64 * 1024];
  bf16x8 v3 = *(const bf16x8*)&gsrc[64 * 1024 + 1024];

  for (int p2 = 0; p2 < 8; ++p2) {
    PHASE(4 * p2,     K0, V0, K1, V1)
    PHASE(4 * p2 + 2, K2, V2, K3, V3)
  }

  // ---- epilogue: O / Osum, store bf16
#pragma unroll
  for (int r = 0; r < 16; ++r) {
    const int qrow = (r & 3) + 8 * (r >> 2) + 4 * h;
    const float rs = 1.0f / Osum[r];
    o[base + (size_t)(q0 + qrow) * 1024 + l31]      = (__bf16)(O[0][r] * rs);
    o[base + (size_t)(q0 + qrow) * 1024 + 32 + l31] = (__bf16)(O[1][r] * rs);
  }
}

// ---------------- launch ----------------
extern "C" void kernel_launch(void* const* d_in, const int* in_sizes, int n_in,
                              void* d_out, int out_size, void* d_ws, size_t ws_size,
                              hipStream_t stream) {
  const float* x  = (const float*)d_in[0];
  const float* Wq = (const float*)d_in[1];
  const float* bq = (const float*)d_in[2];
  const float* Wo = (const float*)d_in[3];
  const float* bo = (const float*)d_in[4];

  char* ws = (char*)d_ws;
  __bf16* xb  = (__bf16*)(ws);                          // [0,8)   x bf16
  __bf16* ab  = (__bf16*)(ws);                          // [0,8)   attn out (aliases xb; xb dead)
  __bf16* wqb = (__bf16*)(ws + ((size_t)8  << 20));     // [8,10)
  __bf16* wob = (__bf16*)(ws + ((size_t)10 << 20));     // [10,12)
  __bf16* qb  = (__bf16*)(ws + ((size_t)12 << 20));     // [12,20) q projection

  const int M = 4096, N = 1024, K = 1024;

  k_cvt3<<<6144, 256, 0, stream>>>(x, Wq, Wo, xb, wqb, wob);

  k_gemm_bt<true ><<<dim3(16, 32), 256, 0, stream>>>(xb, wqb, bq, qb, M, N, K);
  k_attn          <<<dim3(16, 32), 256, 0, stream>>>(qb, ab);
  k_gemm_bt<false><<<dim3(16, 32), 256, 0, stream>>>(ab, wob, bo, d_out, M, N, K);
}

// Round 24
// 93.982 us; speedup vs baseline: 1.1018x; 1.0016x over previous
//
#include <hip/hip_runtime.h>
#include <hip/hip_bf16.h>

typedef __bf16 bf16x8 __attribute__((ext_vector_type(8)));
typedef float  f32x4  __attribute__((ext_vector_type(4)));
typedef float  f32x16 __attribute__((ext_vector_type(16)));

// async 16B global -> LDS (wave-uniform LDS base + lane*16)
__device__ __forceinline__ void gload_lds16(const void* g, void* l) {
  __builtin_amdgcn_global_load_lds(
      (const __attribute__((address_space(1))) unsigned int*)g,
      (__attribute__((address_space(3))) unsigned int*)l, 16, 0, 0);
}

// XCD-aware bijective remap for a (16, 32) grid: blocks sharing y land on ONE XCD.
__device__ __forceinline__ void xcd_remap(int& x, int& y) {
  const int lin = blockIdx.x + (blockIdx.y << 4);   // 0..511
  const int xcd = lin & 7, slot = lin >> 3;         // slot 0..63
  y = ((slot >> 4) << 3) + xcd;                     // 0..31
  x = slot & 15;                                    // 0..15
}

// ---------------- fused fp32 -> bf16 convert: x, Wq, Wo in one launch ----------------
__global__ void k_cvt3(const float* __restrict__ x, const float* __restrict__ wq,
                       const float* __restrict__ wo, __bf16* __restrict__ xb,
                       __bf16* __restrict__ wqb, __bf16* __restrict__ wob) {
  const int i = blockIdx.x * 256 + threadIdx.x;     // x 1M f4, wq 256K, wo 256K
  const float* s; __bf16* d; int j;
  if (i < 1048576)      { s = x;  d = xb;  j = i; }
  else if (i < 1310720) { s = wq; d = wqb; j = i - 1048576; }
  else                  { s = wo; d = wob; j = i - 1310720; }
  float4 v = ((const float4*)s)[j];
  union { __bf16 h[4]; uint2 u; } o;
  o.h[0] = (__bf16)v.x; o.h[1] = (__bf16)v.y;
  o.h[2] = (__bf16)v.z; o.h[3] = (__bf16)v.w;
  ((uint2*)d)[j] = o.u;
}

// ---------------- C[M,N] = A[M,K] @ B[N,K]^T + bias ---------------- (r22 proven, verbatim)
template<bool OUT_BF16>
__global__ __launch_bounds__(256, 2)
void k_gemm_bt(const __bf16* __restrict__ A, const __bf16* __restrict__ B,
               const float* __restrict__ bias, void* __restrict__ C,
               int M, int N, int K) {
  __shared__ __align__(16) __bf16 At[4][128 * 32];   // 32KB
  __shared__ __align__(16) __bf16 Bt[4][64 * 32];    // 16KB
  const int tid  = threadIdx.x;
  const int lane = tid & 63;
  const int w    = tid >> 6;
  const int wr   = w >> 1, wc = w & 1;
  int bx, by; xcd_remap(bx, by);
  const int bm = by * 128, bn = bx * 64;

  f32x4 acc[4][2] = {};

  const __bf16* ga = A + (size_t)(bm + (tid >> 2)) * K + (tid & 3) * 8;
  const __bf16* gb = B + (size_t)(bn + (tid >> 2)) * K + (tid & 3) * 8;

#pragma unroll
  for (int p = 0; p < 2; ++p) {
    gload_lds16(ga + p * 32,                  &At[p][(w * 16) * 32]);
    gload_lds16(ga + p * 32 + (size_t)64 * K, &At[p][(64 + w * 16) * 32]);
    gload_lds16(gb + p * 32,                  &Bt[p][(w * 16) * 32]);
  }

  const int NIT = K / 32;                      // 32
  for (int it = 0; it < NIT; ++it) {
    const int cur = it & 3;
    if (it + 2 < NIT) {
      const int nb = (it + 2) & 3;
      const int k2 = (it + 2) * 32;
      gload_lds16(ga + k2,                  &At[nb][(w * 16) * 32]);
      gload_lds16(ga + k2 + (size_t)64 * K, &At[nb][(64 + w * 16) * 32]);
      gload_lds16(gb + k2,                  &Bt[nb][(w * 16) * 32]);
      asm volatile("s_waitcnt vmcnt(6)" ::: "memory");
    } else if (it + 2 == NIT) {
      asm volatile("s_waitcnt vmcnt(3)" ::: "memory");
    } else {
      asm volatile("s_waitcnt vmcnt(0)" ::: "memory");
    }
    __builtin_amdgcn_s_barrier();
    __builtin_amdgcn_sched_barrier(0);

    bf16x8 a[4], b[2];
#pragma unroll
    for (int mt = 0; mt < 4; ++mt)
      a[mt] = *(const bf16x8*)&At[cur][(wr * 64 + mt * 16 + (lane & 15)) * 32 + (lane >> 4) * 8];
#pragma unroll
    for (int nt = 0; nt < 2; ++nt)
      b[nt] = *(const bf16x8*)&Bt[cur][(wc * 32 + nt * 16 + (lane & 15)) * 32 + (lane >> 4) * 8];
    __builtin_amdgcn_s_setprio(1);
#pragma unroll
    for (int mt = 0; mt < 4; ++mt)
#pragma unroll
      for (int nt = 0; nt < 2; ++nt)
        acc[mt][nt] = __builtin_amdgcn_mfma_f32_16x16x32_bf16(a[mt], b[nt], acc[mt][nt], 0, 0, 0);
    __builtin_amdgcn_s_setprio(0);
  }

#pragma unroll
  for (int nt = 0; nt < 2; ++nt) {
    const int col = bn + wc * 32 + nt * 16 + (lane & 15);
    const float bv = bias[col];
#pragma unroll
    for (int mt = 0; mt < 4; ++mt) {
#pragma unroll
      for (int r = 0; r < 4; ++r) {
        const int row = bm + wr * 64 + mt * 16 + (lane >> 4) * 4 + r;
        const float v = acc[mt][nt][r] + bv;
        if (OUT_BF16) ((__bf16*)C)[(size_t)row * N + col] = (__bf16)v;
        else          ((float*)C)[(size_t)row * N + col]  = v;
      }
    }
  }
}

// ---------------- flash attention (Q = K = V), 32x32x16, PAIR-PHASE ---------------- (r23 proven)
#define SWZ2(row, col) ((row) * 64 + ((col) ^ (((((row) & 7) ^ ((row) >> 3)) & 7) << 3)))

#define WRITE_TILE(KB, VB, va, vb2)                                           \
    *(bf16x8*)&KB[SWZ2(2 * sm, c0)]     = va;                                 \
    *(bf16x8*)&KB[SWZ2(2 * sm + 1, c0)] = vb2;                                \
    _Pragma("unroll")                                                         \
    for (int j = 0; j < 8; ++j) {                                             \
      union { __bf16 b[2]; unsigned u; } pk;                                  \
      pk.b[0] = va[j]; pk.b[1] = vb2[j];                                      \
      *(unsigned*)&VB[SWZ2(c0 + j, 2 * sm)] = pk.u;                           \
    }

#define COMPUTE_TILE(KB, VB)                                                  \
  {                                                                           \
    f32x16 s[2] = {};                                                         \
    _Pragma("unroll")                                                         \
    for (int kvf = 0; kvf < 2; ++kvf) {                                       \
      __builtin_amdgcn_s_setprio(1);                                          \
      _Pragma("unroll")                                                       \
      for (int ks = 0; ks < 4; ++ks) {                                        \
        bf16x8 ka = *(const bf16x8*)&KB[SWZ2(kvf * 32 + l31, ks * 16 + h * 8)]; \
        s[kvf] = __builtin_amdgcn_mfma_f32_32x32x16_bf16(ka, qb[ks], s[kvf], 0, 0, 0); \
      }                                                                       \
      __builtin_amdgcn_s_setprio(0);                                          \
    }                                                                         \
    unsigned P[2][4][2];                                                      \
    _Pragma("unroll")                                                         \
    for (int kvf = 0; kvf < 2; ++kvf) {                                       \
      _Pragma("unroll")                                                       \
      for (int rq = 0; rq < 4; ++rq) {                                        \
        _Pragma("unroll")                                                     \
        for (int tt = 0; tt < 2; ++tt) {                                      \
          const float p0 = __builtin_amdgcn_exp2f(s[kvf][rq * 4 + tt * 2]);   \
          const float p1 = __builtin_amdgcn_exp2f(s[kvf][rq * 4 + tt * 2 + 1]); \
          union { __bf16 b[2]; unsigned u; } pk;                              \
          pk.b[0] = (__bf16)p0; pk.b[1] = (__bf16)p1;                         \
          P[kvf][rq][tt] = pk.u;                                              \
        }                                                                     \
      }                                                                       \
    }                                                                         \
    _Pragma("unroll")                                                         \
    for (int ko = 0; ko < 4; ++ko) {                                          \
      const int kvf = ko >> 1, rqa = (ko & 1) * 2, rqb = rqa + 1;             \
      asm volatile("v_permlane32_swap_b32 %0, %1"                             \
                   : "+v"(P[kvf][rqa][0]), "+v"(P[kvf][rqb][0]));             \
      asm volatile("v_permlane32_swap_b32 %0, %1"                             \
                   : "+v"(P[kvf][rqa][1]), "+v"(P[kvf][rqb][1]));             \
    }                                                                         \
    __builtin_amdgcn_s_setprio(1);                                            \
    _Pragma("unroll")                                                         \
    for (int ko = 0; ko < 4; ++ko) {                                          \
      const int kvf = ko >> 1, rqa = (ko & 1) * 2, rqb = rqa + 1;             \
      union { unsigned u[4]; bf16x8 v; } pu;                                  \
      pu.u[0] = P[kvf][rqa][0]; pu.u[1] = P[kvf][rqa][1];                     \
      pu.u[2] = P[kvf][rqb][0]; pu.u[3] = P[kvf][rqb][1];                     \
      Osum = __builtin_amdgcn_mfma_f32_32x32x16_bf16(pu.v, onesb, Osum, 0, 0, 0); \
      bf16x8 vb0 = *(const bf16x8*)&VB[SWZ2(l31,      ko * 16 + h * 8)];      \
      bf16x8 vb1 = *(const bf16x8*)&VB[SWZ2(32 + l31, ko * 16 + h * 8)];      \
      O[0] = __builtin_amdgcn_mfma_f32_32x32x16_bf16(pu.v, vb0, O[0], 0, 0, 0); \
      O[1] = __builtin_amdgcn_mfma_f32_32x32x16_bf16(pu.v, vb1, O[1], 0, 0, 0); \
    }                                                                         \
    __builtin_amdgcn_s_setprio(0);                                            \
  }

#define PHASE(T, KA, VA, KB, VB)                                              \
  {                                                                           \
    WRITE_TILE(KA, VA, v0, v1)                                                \
    WRITE_TILE(KB, VB, v2, v3)                                                \
    __syncthreads();                                                          \
    if ((T) < 30) {                                                           \
      v0 = *(const bf16x8*)&gsrc[(size_t)((T) + 2) * 64 * 1024];              \
      v1 = *(const bf16x8*)&gsrc[(size_t)((T) + 2) * 64 * 1024 + 1024];       \
      v2 = *(const bf16x8*)&gsrc[(size_t)((T) + 3) * 64 * 1024];              \
      v3 = *(const bf16x8*)&gsrc[(size_t)((T) + 3) * 64 * 1024 + 1024];       \
    }                                                                         \
    COMPUTE_TILE(KA, VA)                                                      \
    COMPUTE_TILE(KB, VB)                                                      \
  }

__global__ __launch_bounds__(256, 2)
void k_attn(const __bf16* __restrict__ q, __bf16* __restrict__ o) {
  __shared__ __align__(16) __bf16 Kt[4][64 * 64];   // 32KB
  __shared__ __align__(16) __bf16 Vt[4][64 * 64];   // 32KB
  const int tid = threadIdx.x, lane = tid & 63;
  const int w = tid >> 6;
  const int l31 = lane & 31, h = lane >> 5;
  int bqx, bh; xcd_remap(bqx, bh);
  const size_t base = ((size_t)(bh >> 4) * 2048) * 1024 + (bh & 15) * 64;
  const int q0 = bqx * 128 + w * 32;
  const float c2 = 0.18033688f;     // 0.125 * log2(e)

  union { unsigned u[4]; bf16x8 v; } ones_u;
  ones_u.u[0] = 0x3F803F80u; ones_u.u[1] = 0x3F803F80u;
  ones_u.u[2] = 0x3F803F80u; ones_u.u[3] = 0x3F803F80u;
  const bf16x8 onesb = ones_u.v;

  // Q B-frags, PRE-SCALED by c2: col q = q0+l31, k(d) = 16ks + 8h + 0..7
  bf16x8 qb[4];
#pragma unroll
  for (int ks = 0; ks < 4; ++ks) {
    union { bf16x8 v; __bf16 b[8]; } u;
    u.v = *(const bf16x8*)&q[base + (size_t)(q0 + l31) * 1024 + ks * 16 + h * 8];
#pragma unroll
    for (int j = 0; j < 8; ++j) u.b[j] = (__bf16)((float)u.b[j] * c2);
    qb[ks] = u.v;
  }

  f32x16 O[2] = {};                 // row q=(r&3)+8*(r>>2)+4h, col d=32dh+l31
  f32x16 Osum = {};                 // row-sum of P, same row mapping

  // staging: thread covers kv rows 2sm, 2sm+1, cols c0..c0+7
  const int sm = tid >> 3, c0 = (tid & 7) * 8;
  const __bf16* gsrc = q + base + (size_t)(2 * sm) * 1024 + c0;

  __bf16* const K0 = &Kt[0][0];  __bf16* const V0 = &Vt[0][0];
  __bf16* const K1 = &Kt[1][0];  __bf16* const V1 = &Vt[1][0];
  __bf16* const K2 = &Kt[2][0];  __bf16* const V2 = &Vt[2][0];
  __bf16* const K3 = &Kt[3][0];  __bf16* const V3 = &Vt[3][0];

  // prologue: tiles 0,1 into registers
  bf16x8 v0 = *(const bf16x8*)&gsrc[0];
  bf16x8 v1 = *(const bf16x8*)&gsrc[1024];
  bf16x8 v2 = *(const bf16x8*)&gsrc[64 * 1024];
  bf16x8 v3 = *(const bf16x8*)&gsrc[64 * 1024 + 1024];

  for (int p2 = 0; p2 < 8; ++p2) {
    PHASE(4 * p2,     K0, V0, K1, V1)
    PHASE(4 * p2 + 2, K2, V2, K3, V3)
  }

  // ---- epilogue: O / Osum, store bf16
#pragma unroll
  for (int r = 0; r < 16; ++r) {
    const int qrow = (r & 3) + 8 * (r >> 2) + 4 * h;
    const float rs = 1.0f / Osum[r];
    o[base + (size_t)(q0 + qrow) * 1024 + l31]      = (__bf16)(O[0][r] * rs);
    o[base + (size_t)(q0 + qrow) * 1024 + 32 + l31] = (__bf16)(O[1][r] * rs);
  }
}

// ---------------- launch ----------------
extern "C" void kernel_launch(void* const* d_in, const int* in_sizes, int n_in,
                              void* d_out, int out_size, void* d_ws, size_t ws_size,
                              hipStream_t stream) {
  const float* x  = (const float*)d_in[0];
  const float* Wq = (const float*)d_in[1];
  const float* bq = (const float*)d_in[2];
  const float* Wo = (const float*)d_in[3];
  const float* bo = (const float*)d_in[4];

  char* ws = (char*)d_ws;
  __bf16* xb  = (__bf16*)(ws);                          // [0,8)   x bf16
  __bf16* ab  = (__bf16*)(ws);                          // [0,8)   attn out (aliases xb; xb dead)
  __bf16* wqb = (__bf16*)(ws + ((size_t)8  << 20));     // [8,10)
  __bf16* wob = (__bf16*)(ws + ((size_t)10 << 20));     // [10,12)
  __bf16* qb  = (__bf16*)(ws + ((size_t)12 << 20));     // [12,20) q projection

  const int M = 4096, N = 1024, K = 1024;

  k_cvt3<<<6144, 256, 0, stream>>>(x, Wq, Wo, xb, wqb, wob);

  k_gemm_bt<true ><<<dim3(16, 32), 256, 0, stream>>>(xb, wqb, bq, qb, M, N, K);
  k_attn          <<<dim3(16, 32), 256, 0, stream>>>(qb, ab);
  k_gemm_bt<false><<<dim3(16, 32), 256, 0, stream>>>(ab, wob, bo, d_out, M, N, K);
}